// Round 3
// baseline (972.103 us; speedup 1.0000x reference)
//
#include <hip/hip_runtime.h>

// GCN 3-layer encoder. Per layer:
//   y   = (X W) * dis[row]                      (dis = rsqrt(deg), deg incl self-loop)
//   out = (y[d] + sum_{e: s->d} y[s]) * dis[d] + b   (+relu)
// CSR built per call (histogram -> scan -> fill); aggregation = gather per node
// (wave per node, lane = feature). GEMM = LDS-tiled, register-blocked fp32.

// ---------------- CSR build ----------------

__global__ void hist_kernel(const int* __restrict__ dst, int* __restrict__ deg, int E) {
  int e = blockIdx.x * blockDim.x + threadIdx.x;
  if (e < E) atomicAdd(&deg[dst[e]], 1);
}

__global__ void scanA_kernel(const int* __restrict__ deg, int* __restrict__ partial,
                             int* __restrict__ bsum, int n) {
  __shared__ int tmp[256];
  int t = threadIdx.x;
  int i = blockIdx.x * 256 + t;
  int v = (i < n) ? deg[i] : 0;
  tmp[t] = v;
  __syncthreads();
  for (int off = 1; off < 256; off <<= 1) {
    int a = (t >= off) ? tmp[t - off] : 0;
    __syncthreads();
    tmp[t] += a;
    __syncthreads();
  }
  if (i < n) partial[i] = tmp[t] - v;  // exclusive
  if (t == 255) bsum[blockIdx.x] = tmp[t];
}

__global__ void scanB_kernel(const int* __restrict__ bsum, int* __restrict__ boff, int nb) {
  __shared__ int tmp[512];
  int t = threadIdx.x;
  int v = (t < nb) ? bsum[t] : 0;
  tmp[t] = v;
  __syncthreads();
  for (int off = 1; off < 512; off <<= 1) {
    int a = (t >= off) ? tmp[t - off] : 0;
    __syncthreads();
    tmp[t] += a;
    __syncthreads();
  }
  if (t < nb) boff[t] = tmp[t] - v;  // exclusive
}

__global__ void scanC_kernel(const int* __restrict__ partial, const int* __restrict__ boff,
                             const int* __restrict__ deg, int* __restrict__ row_ptr,
                             int* __restrict__ cursor, float* __restrict__ dis, int n, int E) {
  int i = blockIdx.x * blockDim.x + threadIdx.x;
  if (i < n) {
    int rp = partial[i] + boff[i >> 8];
    row_ptr[i] = rp;
    cursor[i] = rp;
    dis[i] = rsqrtf((float)deg[i] + 1.0f);  // +1 = self-loop
  } else if (i == n) {
    row_ptr[n] = E;
  }
}

__global__ void fill_kernel(const int* __restrict__ src, const int* __restrict__ dst,
                            int* __restrict__ cursor, int* __restrict__ csr_src, int E) {
  int e = blockIdx.x * blockDim.x + threadIdx.x;
  if (e < E) {
    int pos = atomicAdd(&cursor[dst[e]], 1);
    csr_src[pos] = src[e];
  }
}

// ---------------- tiled GEMM ----------------
// X[n x 64] @ W[64 x M] * dis[row] -> y.  64-row tile per block, 256 threads.
// Thread tile: 4 rows x 4 cols (M=64) or 4 rows x (4+4) cols at c0, c0+64 (M=128).
// Xs padded to stride 68 (banks: 4 r-groups -> 2-way max, free). Ws row stride M:
// c0 spacing 4 across 16 lane-groups -> 2-way max, free.
template <int M>
__global__ __launch_bounds__(256) void gemm_tiled(const float* __restrict__ X,
                                                  const float* __restrict__ W,
                                                  const float* __restrict__ dis,
                                                  float* __restrict__ y, int n) {
  constexpr int CT = M / 64;  // col tiles per thread (1 or 2)
  __shared__ float Xs[64 * 68];
  __shared__ float Ws[64 * M];
  int tid = threadIdx.x;
  int rb = blockIdx.x * 64;

  // stage W (flat K*M copy, coalesced float4)
  constexpr int WN = 64 * M / 4;
  for (int i = tid; i < WN; i += 256) {
    ((float4*)Ws)[i] = ((const float4*)W)[i];
  }
  // stage X tile: i -> (r = i/16, kq = i%16); 16 lanes cover one 256B row
  for (int i = tid; i < 1024; i += 256) {
    int r = i >> 4, kq = i & 15;
    int gr = rb + r;
    float4 v = make_float4(0.f, 0.f, 0.f, 0.f);
    if (gr < n) v = ((const float4*)(X + (size_t)gr * 64))[kq];
    *(float4*)&Xs[r * 68 + kq * 4] = v;
  }
  __syncthreads();

  int r0 = (tid >> 4) << 2;  // 0..60
  int c0 = (tid & 15) << 2;  // 0..60

  float acc[4][CT][4] = {};

#pragma unroll
  for (int kc = 0; kc < 64; kc += 4) {
    float4 xa[4];
#pragma unroll
    for (int ri = 0; ri < 4; ++ri) xa[ri] = *(const float4*)&Xs[(r0 + ri) * 68 + kc];
    float4 wb[4][CT];
#pragma unroll
    for (int kk = 0; kk < 4; ++kk)
#pragma unroll
      for (int ct = 0; ct < CT; ++ct)
        wb[kk][ct] = *(const float4*)&Ws[(kc + kk) * M + c0 + ct * 64];
#pragma unroll
    for (int ri = 0; ri < 4; ++ri) {
      const float* xv = (const float*)&xa[ri];
#pragma unroll
      for (int kk = 0; kk < 4; ++kk) {
        float xk = xv[kk];
#pragma unroll
        for (int ct = 0; ct < CT; ++ct) {
          const float* wv = (const float*)&wb[kk][ct];
          acc[ri][ct][0] = fmaf(xk, wv[0], acc[ri][ct][0]);
          acc[ri][ct][1] = fmaf(xk, wv[1], acc[ri][ct][1]);
          acc[ri][ct][2] = fmaf(xk, wv[2], acc[ri][ct][2]);
          acc[ri][ct][3] = fmaf(xk, wv[3], acc[ri][ct][3]);
        }
      }
    }
  }

#pragma unroll
  for (int ri = 0; ri < 4; ++ri) {
    int gr = rb + r0 + ri;
    if (gr >= n) continue;
    float sc = dis[gr];
#pragma unroll
    for (int ct = 0; ct < CT; ++ct) {
      float4 v;
      v.x = acc[ri][ct][0] * sc;
      v.y = acc[ri][ct][1] * sc;
      v.z = acc[ri][ct][2] * sc;
      v.w = acc[ri][ct][3] * sc;
      *(float4*)&y[(size_t)gr * M + c0 + ct * 64] = v;
    }
  }
}

// ---------------- gather ----------------
// One wave per node: out[d] = (y[d] + sum y[s]) * dis[d] + b  (+relu).
template <int M, bool RELU>
__global__ void gather_kernel(const int* __restrict__ row_ptr, const int* __restrict__ csr_src,
                              const float* __restrict__ y, const float* __restrict__ dis,
                              const float* __restrict__ b, float* __restrict__ out, int n) {
  int node = blockIdx.x * (blockDim.x >> 6) + (threadIdx.x >> 6);
  int lane = threadIdx.x & 63;
  if (node >= n) return;
  int beg = row_ptr[node];
  int end = row_ptr[node + 1];
  float acc0 = y[(size_t)node * M + lane];  // self-loop
  float acc1 = 0.0f;
  if (M == 128) acc1 = y[(size_t)node * M + 64 + lane];
  int k = beg;
  for (; k + 1 < end; k += 2) {
    int s0 = csr_src[k];
    int s1 = csr_src[k + 1];
    acc0 += y[(size_t)s0 * M + lane];
    if (M == 128) acc1 += y[(size_t)s0 * M + 64 + lane];
    acc0 += y[(size_t)s1 * M + lane];
    if (M == 128) acc1 += y[(size_t)s1 * M + 64 + lane];
  }
  if (k < end) {
    int s0 = csr_src[k];
    acc0 += y[(size_t)s0 * M + lane];
    if (M == 128) acc1 += y[(size_t)s0 * M + 64 + lane];
  }
  float sc = dis[node];
  float v0 = acc0 * sc + b[lane];
  if (RELU) v0 = fmaxf(v0, 0.0f);
  out[(size_t)node * M + lane] = v0;
  if (M == 128) {
    float v1 = acc1 * sc + b[64 + lane];
    if (RELU) v1 = fmaxf(v1, 0.0f);
    out[(size_t)node * M + 64 + lane] = v1;
  }
}

// ---------------- launch ----------------

extern "C" void kernel_launch(void* const* d_in, const int* in_sizes, int n_in,
                              void* d_out, int out_size, void* d_ws, size_t ws_size,
                              hipStream_t stream) {
  const float* x  = (const float*)d_in[0];
  const float* W1 = (const float*)d_in[1];
  const float* b1 = (const float*)d_in[2];
  const float* W2 = (const float*)d_in[3];
  const float* b2 = (const float*)d_in[4];
  const float* W3 = (const float*)d_in[5];
  const float* b3 = (const float*)d_in[6];
  const int*   ei = (const int*)d_in[7];

  const int n = in_sizes[0] / 64;   // 100000
  const int E = in_sizes[7] / 2;    // 1000000
  const int* src = ei;
  const int* dst = ei + E;

  // Workspace: floats dis[n] | y[n*128] | h[n*64], then ints
  float* dis = (float*)d_ws;
  float* y   = dis + n;
  float* h   = y + (size_t)n * 128;
  int* deg     = (int*)(h + (size_t)n * 64);
  int* partial = deg + n;
  int* bsum    = partial + n;
  int* boff    = bsum + 512;
  int* row_ptr = boff + 512;
  int* cursor  = row_ptr + (n + 1);
  int* csr_src = cursor + n;
  float* out = (float*)d_out;

  dim3 blk(256);
  int gN  = (n + 255) / 256;
  int gN1 = (n + 256) / 256;
  int gE  = (E + 255) / 256;
  int gW  = (n + 3) / 4;          // gather: 4 waves (nodes) per block
  int gT  = (n + 63) / 64;        // gemm: 64-row tiles

  // --- CSR build + dis ---
  hipMemsetAsync(deg, 0, (size_t)n * sizeof(int), stream);
  hist_kernel<<<gE, blk, 0, stream>>>(dst, deg, E);
  scanA_kernel<<<gN, blk, 0, stream>>>(deg, partial, bsum, n);
  scanB_kernel<<<1, 512, 0, stream>>>(bsum, boff, gN);
  scanC_kernel<<<gN1, blk, 0, stream>>>(partial, boff, deg, row_ptr, cursor, dis, n, E);
  fill_kernel<<<gE, blk, 0, stream>>>(src, dst, cursor, csr_src, E);

  // --- Layer 1 ---
  gemm_tiled<64><<<gT, blk, 0, stream>>>(x, W1, dis, y, n);
  gather_kernel<64, true><<<gW, blk, 0, stream>>>(row_ptr, csr_src, y, dis, b1, h, n);

  // --- Layer 2 ---
  gemm_tiled<64><<<gT, blk, 0, stream>>>(h, W2, dis, y, n);
  gather_kernel<64, true><<<gW, blk, 0, stream>>>(row_ptr, csr_src, y, dis, b2, h, n);

  // --- Layer 3 ---
  gemm_tiled<128><<<gT, blk, 0, stream>>>(h, W3, dis, y, n);
  gather_kernel<128, false><<<gW, blk, 0, stream>>>(row_ptr, csr_src, y, dis, b3, out, n);
}

// Round 4
// 965.051 us; speedup vs baseline: 1.0073x; 1.0073x over previous
//
#include <hip/hip_runtime.h>

// GCN 3-layer encoder. Per layer:
//   y   = (X W) * dis[row]                      (dis = rsqrt(deg), deg incl self-loop)
//   out = (y[d] + sum_{e: s->d} y[s]) * dis[d] + b   (+relu)
// CSR built per call (histogram -> scan -> fill); aggregation = gather per node
// (wave per node, lane = feature). GEMM = LDS-tiled, register-blocked fp32.
// NOTE: never take the address of register arrays (float4 casts) — round 3
// showed that spills everything to scratch (256 VGPR, 738 MB scratch fetch).

// ---------------- CSR build ----------------

__global__ void hist_kernel(const int* __restrict__ dst, int* __restrict__ deg, int E) {
  int e = blockIdx.x * blockDim.x + threadIdx.x;
  if (e < E) atomicAdd(&deg[dst[e]], 1);
}

__global__ void scanA_kernel(const int* __restrict__ deg, int* __restrict__ partial,
                             int* __restrict__ bsum, int n) {
  __shared__ int tmp[256];
  int t = threadIdx.x;
  int i = blockIdx.x * 256 + t;
  int v = (i < n) ? deg[i] : 0;
  tmp[t] = v;
  __syncthreads();
  for (int off = 1; off < 256; off <<= 1) {
    int a = (t >= off) ? tmp[t - off] : 0;
    __syncthreads();
    tmp[t] += a;
    __syncthreads();
  }
  if (i < n) partial[i] = tmp[t] - v;  // exclusive
  if (t == 255) bsum[blockIdx.x] = tmp[t];
}

__global__ void scanB_kernel(const int* __restrict__ bsum, int* __restrict__ boff, int nb) {
  __shared__ int tmp[512];
  int t = threadIdx.x;
  int v = (t < nb) ? bsum[t] : 0;
  tmp[t] = v;
  __syncthreads();
  for (int off = 1; off < 512; off <<= 1) {
    int a = (t >= off) ? tmp[t - off] : 0;
    __syncthreads();
    tmp[t] += a;
    __syncthreads();
  }
  if (t < nb) boff[t] = tmp[t] - v;  // exclusive
}

__global__ void scanC_kernel(const int* __restrict__ partial, const int* __restrict__ boff,
                             const int* __restrict__ deg, int* __restrict__ row_ptr,
                             int* __restrict__ cursor, float* __restrict__ dis, int n, int E) {
  int i = blockIdx.x * blockDim.x + threadIdx.x;
  if (i < n) {
    int rp = partial[i] + boff[i >> 8];
    row_ptr[i] = rp;
    cursor[i] = rp;
    dis[i] = rsqrtf((float)deg[i] + 1.0f);  // +1 = self-loop
  } else if (i == n) {
    row_ptr[n] = E;
  }
}

__global__ void fill_kernel(const int* __restrict__ src, const int* __restrict__ dst,
                            int* __restrict__ cursor, int* __restrict__ csr_src, int E) {
  int e = blockIdx.x * blockDim.x + threadIdx.x;
  if (e < E) {
    int pos = atomicAdd(&cursor[dst[e]], 1);
    csr_src[pos] = src[e];
  }
}

// ---------------- tiled GEMM ----------------

__device__ __forceinline__ void fma4(float4& a, float s, const float4 w) {
  a.x = fmaf(s, w.x, a.x);
  a.y = fmaf(s, w.y, a.y);
  a.z = fmaf(s, w.z, a.z);
  a.w = fmaf(s, w.w, a.w);
}

// X[n x 64] @ W[64 x M] * dis[row] -> y.  64-row tile per block, 256 threads.
// Thread tile: 4 rows x 4 cols (M=64) or 4 rows x (4,4) cols at c0, c0+64 (M=128).
template <int M>
__global__ __launch_bounds__(256) void gemm_tiled(const float* __restrict__ X,
                                                  const float* __restrict__ W,
                                                  const float* __restrict__ dis,
                                                  float* __restrict__ y, int n) {
  constexpr int CT = M / 64;  // col tiles per thread (1 or 2)
  __shared__ float Xs[64 * 68];
  __shared__ float Ws[64 * M];
  int tid = threadIdx.x;
  int rb = blockIdx.x * 64;

  // stage W (flat copy, coalesced float4)
  constexpr int WN = 64 * M / 4;
  for (int i = tid; i < WN; i += 256) {
    ((float4*)Ws)[i] = ((const float4*)W)[i];
  }
  // stage X tile: i -> (r = i/16, kq = i%16)
  for (int i = tid; i < 1024; i += 256) {
    int r = i >> 4, kq = i & 15;
    int gr = rb + r;
    float4 v = make_float4(0.f, 0.f, 0.f, 0.f);
    if (gr < n) v = ((const float4*)(X + (size_t)gr * 64))[kq];
    *(float4*)&Xs[r * 68 + kq * 4] = v;
  }
  __syncthreads();

  int r0 = (tid >> 4) << 2;  // 0..60
  int c0 = (tid & 15) << 2;  // 0..60

  float4 acc[4][CT];
#pragma unroll
  for (int ri = 0; ri < 4; ++ri)
#pragma unroll
    for (int ct = 0; ct < CT; ++ct) acc[ri][ct] = make_float4(0.f, 0.f, 0.f, 0.f);

#pragma unroll
  for (int kc = 0; kc < 64; kc += 4) {
    float4 x0 = *(const float4*)&Xs[(r0 + 0) * 68 + kc];
    float4 x1 = *(const float4*)&Xs[(r0 + 1) * 68 + kc];
    float4 x2 = *(const float4*)&Xs[(r0 + 2) * 68 + kc];
    float4 x3 = *(const float4*)&Xs[(r0 + 3) * 68 + kc];
#pragma unroll
    for (int ct = 0; ct < CT; ++ct) {
      int cc = c0 + ct * 64;
      float4 w0 = *(const float4*)&Ws[(kc + 0) * M + cc];
      float4 w1 = *(const float4*)&Ws[(kc + 1) * M + cc];
      float4 w2 = *(const float4*)&Ws[(kc + 2) * M + cc];
      float4 w3 = *(const float4*)&Ws[(kc + 3) * M + cc];
      fma4(acc[0][ct], x0.x, w0); fma4(acc[0][ct], x0.y, w1);
      fma4(acc[0][ct], x0.z, w2); fma4(acc[0][ct], x0.w, w3);
      fma4(acc[1][ct], x1.x, w0); fma4(acc[1][ct], x1.y, w1);
      fma4(acc[1][ct], x1.z, w2); fma4(acc[1][ct], x1.w, w3);
      fma4(acc[2][ct], x2.x, w0); fma4(acc[2][ct], x2.y, w1);
      fma4(acc[2][ct], x2.z, w2); fma4(acc[2][ct], x2.w, w3);
      fma4(acc[3][ct], x3.x, w0); fma4(acc[3][ct], x3.y, w1);
      fma4(acc[3][ct], x3.z, w2); fma4(acc[3][ct], x3.w, w3);
    }
  }

#pragma unroll
  for (int ri = 0; ri < 4; ++ri) {
    int gr = rb + r0 + ri;
    if (gr >= n) continue;
    float sc = dis[gr];
#pragma unroll
    for (int ct = 0; ct < CT; ++ct) {
      float4 v = acc[ri][ct];
      v.x *= sc; v.y *= sc; v.z *= sc; v.w *= sc;
      *(float4*)&y[(size_t)gr * M + c0 + ct * 64] = v;
    }
  }
}

// ---------------- gather ----------------
// One wave per node: out[d] = (y[d] + sum y[s]) * dis[d] + b  (+relu).
template <int M, bool RELU>
__global__ void gather_kernel(const int* __restrict__ row_ptr, const int* __restrict__ csr_src,
                              const float* __restrict__ y, const float* __restrict__ dis,
                              const float* __restrict__ b, float* __restrict__ out, int n) {
  int node = blockIdx.x * (blockDim.x >> 6) + (threadIdx.x >> 6);
  int lane = threadIdx.x & 63;
  if (node >= n) return;
  int beg = row_ptr[node];
  int end = row_ptr[node + 1];
  float acc0 = y[(size_t)node * M + lane];  // self-loop
  float acc1 = 0.0f;
  if (M == 128) acc1 = y[(size_t)node * M + 64 + lane];
  int k = beg;
  for (; k + 1 < end; k += 2) {
    int s0 = csr_src[k];
    int s1 = csr_src[k + 1];
    acc0 += y[(size_t)s0 * M + lane];
    if (M == 128) acc1 += y[(size_t)s0 * M + 64 + lane];
    acc0 += y[(size_t)s1 * M + lane];
    if (M == 128) acc1 += y[(size_t)s1 * M + 64 + lane];
  }
  if (k < end) {
    int s0 = csr_src[k];
    acc0 += y[(size_t)s0 * M + lane];
    if (M == 128) acc1 += y[(size_t)s0 * M + 64 + lane];
  }
  float sc = dis[node];
  float v0 = acc0 * sc + b[lane];
  if (RELU) v0 = fmaxf(v0, 0.0f);
  out[(size_t)node * M + lane] = v0;
  if (M == 128) {
    float v1 = acc1 * sc + b[64 + lane];
    if (RELU) v1 = fmaxf(v1, 0.0f);
    out[(size_t)node * M + 64 + lane] = v1;
  }
}

// ---------------- launch ----------------

extern "C" void kernel_launch(void* const* d_in, const int* in_sizes, int n_in,
                              void* d_out, int out_size, void* d_ws, size_t ws_size,
                              hipStream_t stream) {
  const float* x  = (const float*)d_in[0];
  const float* W1 = (const float*)d_in[1];
  const float* b1 = (const float*)d_in[2];
  const float* W2 = (const float*)d_in[3];
  const float* b2 = (const float*)d_in[4];
  const float* W3 = (const float*)d_in[5];
  const float* b3 = (const float*)d_in[6];
  const int*   ei = (const int*)d_in[7];

  const int n = in_sizes[0] / 64;   // 100000
  const int E = in_sizes[7] / 2;    // 1000000
  const int* src = ei;
  const int* dst = ei + E;

  // Workspace: floats dis[n] | y[n*128] | h[n*64], then ints
  float* dis = (float*)d_ws;
  float* y   = dis + n;
  float* h   = y + (size_t)n * 128;
  int* deg     = (int*)(h + (size_t)n * 64);
  int* partial = deg + n;
  int* bsum    = partial + n;
  int* boff    = bsum + 512;
  int* row_ptr = boff + 512;
  int* cursor  = row_ptr + (n + 1);
  int* csr_src = cursor + n;
  float* out = (float*)d_out;

  dim3 blk(256);
  int gN  = (n + 255) / 256;
  int gN1 = (n + 256) / 256;
  int gE  = (E + 255) / 256;
  int gW  = (n + 3) / 4;          // gather: 4 waves (nodes) per block
  int gT  = (n + 63) / 64;        // gemm: 64-row tiles

  // --- CSR build + dis ---
  hipMemsetAsync(deg, 0, (size_t)n * sizeof(int), stream);
  hist_kernel<<<gE, blk, 0, stream>>>(dst, deg, E);
  scanA_kernel<<<gN, blk, 0, stream>>>(deg, partial, bsum, n);
  scanB_kernel<<<1, 512, 0, stream>>>(bsum, boff, gN);
  scanC_kernel<<<gN1, blk, 0, stream>>>(partial, boff, deg, row_ptr, cursor, dis, n, E);
  fill_kernel<<<gE, blk, 0, stream>>>(src, dst, cursor, csr_src, E);

  // --- Layer 1 ---
  gemm_tiled<64><<<gT, blk, 0, stream>>>(x, W1, dis, y, n);
  gather_kernel<64, true><<<gW, blk, 0, stream>>>(row_ptr, csr_src, y, dis, b1, h, n);

  // --- Layer 2 ---
  gemm_tiled<64><<<gT, blk, 0, stream>>>(h, W2, dis, y, n);
  gather_kernel<64, true><<<gW, blk, 0, stream>>>(row_ptr, csr_src, y, dis, b2, h, n);

  // --- Layer 3 ---
  gemm_tiled<128><<<gT, blk, 0, stream>>>(h, W3, dis, y, n);
  gather_kernel<128, false><<<gW, blk, 0, stream>>>(row_ptr, csr_src, y, dis, b3, out, n);
}

// Round 5
// 482.793 us; speedup vs baseline: 2.0135x; 1.9989x over previous
//
#include <hip/hip_runtime.h>

// GCN 3-layer encoder. Per layer:
//   y   = (X W) * dis[row]                      (dis = rsqrt(deg), deg incl self-loop)
//   out = (y[d] + sum_{e: s->d} y[s]) * dis[d] + b   (+relu)
// CSR built per call (histogram -> scan -> fill); aggregation = gather per node
// (wave per node, lane = feature). GEMM = LDS-tiled, register-blocked fp32,
// 64-col slabs (grid.y = M/64), K-loop unroll capped at 2.
// LESSON (r3/r4): full unroll of the 16-step K-loop makes the scheduler hoist
// ~all LDS loads -> 256 VGPR + scratch spill (732 MB fake FETCH). Cap unroll.

// ---------------- CSR build ----------------

__global__ void hist_kernel(const int* __restrict__ dst, int* __restrict__ deg, int E) {
  int e = blockIdx.x * blockDim.x + threadIdx.x;
  if (e < E) atomicAdd(&deg[dst[e]], 1);
}

__global__ void scanA_kernel(const int* __restrict__ deg, int* __restrict__ partial,
                             int* __restrict__ bsum, int n) {
  __shared__ int tmp[256];
  int t = threadIdx.x;
  int i = blockIdx.x * 256 + t;
  int v = (i < n) ? deg[i] : 0;
  tmp[t] = v;
  __syncthreads();
  for (int off = 1; off < 256; off <<= 1) {
    int a = (t >= off) ? tmp[t - off] : 0;
    __syncthreads();
    tmp[t] += a;
    __syncthreads();
  }
  if (i < n) partial[i] = tmp[t] - v;  // exclusive
  if (t == 255) bsum[blockIdx.x] = tmp[t];
}

__global__ void scanB_kernel(const int* __restrict__ bsum, int* __restrict__ boff, int nb) {
  __shared__ int tmp[512];
  int t = threadIdx.x;
  int v = (t < nb) ? bsum[t] : 0;
  tmp[t] = v;
  __syncthreads();
  for (int off = 1; off < 512; off <<= 1) {
    int a = (t >= off) ? tmp[t - off] : 0;
    __syncthreads();
    tmp[t] += a;
    __syncthreads();
  }
  if (t < nb) boff[t] = tmp[t] - v;  // exclusive
}

__global__ void scanC_kernel(const int* __restrict__ partial, const int* __restrict__ boff,
                             const int* __restrict__ deg, int* __restrict__ row_ptr,
                             int* __restrict__ cursor, float* __restrict__ dis, int n, int E) {
  int i = blockIdx.x * blockDim.x + threadIdx.x;
  if (i < n) {
    int rp = partial[i] + boff[i >> 8];
    row_ptr[i] = rp;
    cursor[i] = rp;
    dis[i] = rsqrtf((float)deg[i] + 1.0f);  // +1 = self-loop
  } else if (i == n) {
    row_ptr[n] = E;
  }
}

__global__ void fill_kernel(const int* __restrict__ src, const int* __restrict__ dst,
                            int* __restrict__ cursor, int* __restrict__ csr_src, int E) {
  int e = blockIdx.x * blockDim.x + threadIdx.x;
  if (e < E) {
    int pos = atomicAdd(&cursor[dst[e]], 1);
    csr_src[pos] = src[e];
  }
}

// ---------------- tiled GEMM (64-row x 64-col slab) ----------------

__device__ __forceinline__ void fma4(float4& a, float s, const float4 w) {
  a.x = fmaf(s, w.x, a.x);
  a.y = fmaf(s, w.y, a.y);
  a.z = fmaf(s, w.z, a.z);
  a.w = fmaf(s, w.w, a.w);
}

// X[n x 64] @ W[64 x ldw] (cols [cb,cb+64)) * dis[row] -> y (stride ldw).
// 256 threads; thread tile 4 rows x 4 cols.
__global__ __launch_bounds__(256, 4) void gemm64(const float* __restrict__ X,
                                                 const float* __restrict__ W,
                                                 const float* __restrict__ dis,
                                                 float* __restrict__ y, int n, int ldw) {
  __shared__ float Xs[64 * 68];
  __shared__ float Ws[64 * 64];
  int tid = threadIdx.x;
  int rb = blockIdx.x * 64;
  int cb = blockIdx.y * 64;

  // stage W cols [cb,cb+64): thread i -> (k = i/16, c = (i%16)*4)
  for (int i = tid; i < 1024; i += 256) {
    int k = i >> 4, cq = (i & 15) << 2;
    *(float4*)&Ws[k * 64 + cq] = *(const float4*)&W[(size_t)k * ldw + cb + cq];
  }
  // stage X tile (K=64 always): thread i -> (r = i/16, k = (i%16)*4)
  for (int i = tid; i < 1024; i += 256) {
    int r = i >> 4, kq = (i & 15) << 2;
    int gr = rb + r;
    float4 v = make_float4(0.f, 0.f, 0.f, 0.f);
    if (gr < n) v = *(const float4*)&X[(size_t)gr * 64 + kq];
    *(float4*)&Xs[r * 68 + kq] = v;
  }
  __syncthreads();

  int r0 = (tid >> 4) << 2;  // 0..60
  int c0 = (tid & 15) << 2;  // 0..60

  float4 a0 = make_float4(0.f, 0.f, 0.f, 0.f);
  float4 a1 = a0, a2 = a0, a3 = a0;

#pragma unroll 2
  for (int kc = 0; kc < 64; kc += 4) {
    float4 x0 = *(const float4*)&Xs[(r0 + 0) * 68 + kc];
    float4 x1 = *(const float4*)&Xs[(r0 + 1) * 68 + kc];
    float4 x2 = *(const float4*)&Xs[(r0 + 2) * 68 + kc];
    float4 x3 = *(const float4*)&Xs[(r0 + 3) * 68 + kc];
    float4 w0 = *(const float4*)&Ws[(kc + 0) * 64 + c0];
    float4 w1 = *(const float4*)&Ws[(kc + 1) * 64 + c0];
    float4 w2 = *(const float4*)&Ws[(kc + 2) * 64 + c0];
    float4 w3 = *(const float4*)&Ws[(kc + 3) * 64 + c0];
    fma4(a0, x0.x, w0); fma4(a0, x0.y, w1); fma4(a0, x0.z, w2); fma4(a0, x0.w, w3);
    fma4(a1, x1.x, w0); fma4(a1, x1.y, w1); fma4(a1, x1.z, w2); fma4(a1, x1.w, w3);
    fma4(a2, x2.x, w0); fma4(a2, x2.y, w1); fma4(a2, x2.z, w2); fma4(a2, x2.w, w3);
    fma4(a3, x3.x, w0); fma4(a3, x3.y, w1); fma4(a3, x3.z, w2); fma4(a3, x3.w, w3);
  }

  int gr0 = rb + r0;
  size_t base = (size_t)gr0 * ldw + cb + c0;
  if (gr0 + 0 < n) {
    float sc = dis[gr0 + 0];
    float4 v = a0; v.x *= sc; v.y *= sc; v.z *= sc; v.w *= sc;
    *(float4*)&y[base + (size_t)0 * ldw] = v;
  }
  if (gr0 + 1 < n) {
    float sc = dis[gr0 + 1];
    float4 v = a1; v.x *= sc; v.y *= sc; v.z *= sc; v.w *= sc;
    *(float4*)&y[base + (size_t)1 * ldw] = v;
  }
  if (gr0 + 2 < n) {
    float sc = dis[gr0 + 2];
    float4 v = a2; v.x *= sc; v.y *= sc; v.z *= sc; v.w *= sc;
    *(float4*)&y[base + (size_t)2 * ldw] = v;
  }
  if (gr0 + 3 < n) {
    float sc = dis[gr0 + 3];
    float4 v = a3; v.x *= sc; v.y *= sc; v.z *= sc; v.w *= sc;
    *(float4*)&y[base + (size_t)3 * ldw] = v;
  }
}

// ---------------- gather ----------------
// One wave per node: out[d] = (y[d] + sum y[s]) * dis[d] + b  (+relu).
template <int M, bool RELU>
__global__ void gather_kernel(const int* __restrict__ row_ptr, const int* __restrict__ csr_src,
                              const float* __restrict__ y, const float* __restrict__ dis,
                              const float* __restrict__ b, float* __restrict__ out, int n) {
  int node = blockIdx.x * (blockDim.x >> 6) + (threadIdx.x >> 6);
  int lane = threadIdx.x & 63;
  if (node >= n) return;
  int beg = row_ptr[node];
  int end = row_ptr[node + 1];
  float acc0 = y[(size_t)node * M + lane];  // self-loop
  float acc1 = 0.0f;
  if (M == 128) acc1 = y[(size_t)node * M + 64 + lane];
  int k = beg;
  for (; k + 1 < end; k += 2) {
    int s0 = csr_src[k];
    int s1 = csr_src[k + 1];
    acc0 += y[(size_t)s0 * M + lane];
    if (M == 128) acc1 += y[(size_t)s0 * M + 64 + lane];
    acc0 += y[(size_t)s1 * M + lane];
    if (M == 128) acc1 += y[(size_t)s1 * M + 64 + lane];
  }
  if (k < end) {
    int s0 = csr_src[k];
    acc0 += y[(size_t)s0 * M + lane];
    if (M == 128) acc1 += y[(size_t)s0 * M + 64 + lane];
  }
  float sc = dis[node];
  float v0 = acc0 * sc + b[lane];
  if (RELU) v0 = fmaxf(v0, 0.0f);
  out[(size_t)node * M + lane] = v0;
  if (M == 128) {
    float v1 = acc1 * sc + b[64 + lane];
    if (RELU) v1 = fmaxf(v1, 0.0f);
    out[(size_t)node * M + 64 + lane] = v1;
  }
}

// ---------------- launch ----------------

extern "C" void kernel_launch(void* const* d_in, const int* in_sizes, int n_in,
                              void* d_out, int out_size, void* d_ws, size_t ws_size,
                              hipStream_t stream) {
  const float* x  = (const float*)d_in[0];
  const float* W1 = (const float*)d_in[1];
  const float* b1 = (const float*)d_in[2];
  const float* W2 = (const float*)d_in[3];
  const float* b2 = (const float*)d_in[4];
  const float* W3 = (const float*)d_in[5];
  const float* b3 = (const float*)d_in[6];
  const int*   ei = (const int*)d_in[7];

  const int n = in_sizes[0] / 64;   // 100000
  const int E = in_sizes[7] / 2;    // 1000000
  const int* src = ei;
  const int* dst = ei + E;

  // Workspace: floats dis[n] | y[n*128] | h[n*64], then ints
  float* dis = (float*)d_ws;
  float* y   = dis + n;
  float* h   = y + (size_t)n * 128;
  int* deg     = (int*)(h + (size_t)n * 64);
  int* partial = deg + n;
  int* bsum    = partial + n;
  int* boff    = bsum + 512;
  int* row_ptr = boff + 512;
  int* cursor  = row_ptr + (n + 1);
  int* csr_src = cursor + n;
  float* out = (float*)d_out;

  dim3 blk(256);
  int gN  = (n + 255) / 256;
  int gN1 = (n + 256) / 256;
  int gE  = (E + 255) / 256;
  int gW  = (n + 3) / 4;          // gather: 4 waves (nodes) per block
  int gT  = (n + 63) / 64;        // gemm: 64-row tiles

  // --- CSR build + dis ---
  hipMemsetAsync(deg, 0, (size_t)n * sizeof(int), stream);
  hist_kernel<<<gE, blk, 0, stream>>>(dst, deg, E);
  scanA_kernel<<<gN, blk, 0, stream>>>(deg, partial, bsum, n);
  scanB_kernel<<<1, 512, 0, stream>>>(bsum, boff, gN);
  scanC_kernel<<<gN1, blk, 0, stream>>>(partial, boff, deg, row_ptr, cursor, dis, n, E);
  fill_kernel<<<gE, blk, 0, stream>>>(src, dst, cursor, csr_src, E);

  // --- Layer 1 ---
  gemm64<<<dim3(gT, 1), blk, 0, stream>>>(x, W1, dis, y, n, 64);
  gather_kernel<64, true><<<gW, blk, 0, stream>>>(row_ptr, csr_src, y, dis, b1, h, n);

  // --- Layer 2 ---
  gemm64<<<dim3(gT, 1), blk, 0, stream>>>(h, W2, dis, y, n, 64);
  gather_kernel<64, true><<<gW, blk, 0, stream>>>(row_ptr, csr_src, y, dis, b2, h, n);

  // --- Layer 3 ---
  gemm64<<<dim3(gT, 2), blk, 0, stream>>>(h, W3, dis, y, n, 128);
  gather_kernel<128, false><<<gW, blk, 0, stream>>>(row_ptr, csr_src, y, dis, b3, out, n);
}

// Round 6
// 442.608 us; speedup vs baseline: 2.1963x; 1.0908x over previous
//
#include <hip/hip_runtime.h>

// GCN 3-layer encoder, aggregate-first form (A_hat commutes with W):
//   per layer: agg = D^-1/2 (A+I) D^-1/2 X   (gather in dim 64)
//              out = act(agg @ W + b) [* dis for next layer's gather input]
// CSR built per call (histogram -> scan -> fill); gather = wave per node,
// lane = feature, 4-edge unroll for memory-level parallelism.
// LESSON (r3/r4): full unroll of the 16-step GEMM K-loop -> 256 VGPR + scratch
// spill. Keep "#pragma unroll 2".
// LESSON (r5): gather is latency-bound (VALUBusy 18%, 3.7 TB/s) -> more
// independent loads per wave + smaller rows.

// ---------------- CSR build ----------------

__global__ void hist_kernel(const int* __restrict__ dst, int* __restrict__ deg, int E) {
  int e = blockIdx.x * blockDim.x + threadIdx.x;
  if (e < E) atomicAdd(&deg[dst[e]], 1);
}

__global__ void scanA_kernel(const int* __restrict__ deg, int* __restrict__ partial,
                             int* __restrict__ bsum, int n) {
  __shared__ int tmp[256];
  int t = threadIdx.x;
  int i = blockIdx.x * 256 + t;
  int v = (i < n) ? deg[i] : 0;
  tmp[t] = v;
  __syncthreads();
  for (int off = 1; off < 256; off <<= 1) {
    int a = (t >= off) ? tmp[t - off] : 0;
    __syncthreads();
    tmp[t] += a;
    __syncthreads();
  }
  if (i < n) partial[i] = tmp[t] - v;  // exclusive
  if (t == 255) bsum[blockIdx.x] = tmp[t];
}

__global__ void scanB_kernel(const int* __restrict__ bsum, int* __restrict__ boff, int nb) {
  __shared__ int tmp[512];
  int t = threadIdx.x;
  int v = (t < nb) ? bsum[t] : 0;
  tmp[t] = v;
  __syncthreads();
  for (int off = 1; off < 512; off <<= 1) {
    int a = (t >= off) ? tmp[t - off] : 0;
    __syncthreads();
    tmp[t] += a;
    __syncthreads();
  }
  if (t < nb) boff[t] = tmp[t] - v;  // exclusive
}

__global__ void scanC_kernel(const int* __restrict__ partial, const int* __restrict__ boff,
                             const int* __restrict__ deg, int* __restrict__ row_ptr,
                             int* __restrict__ cursor, float* __restrict__ dis, int n, int E) {
  int i = blockIdx.x * blockDim.x + threadIdx.x;
  if (i < n) {
    int rp = partial[i] + boff[i >> 8];
    row_ptr[i] = rp;
    cursor[i] = rp;
    dis[i] = rsqrtf((float)deg[i] + 1.0f);  // +1 = self-loop
  } else if (i == n) {
    row_ptr[n] = E;
  }
}

__global__ void fill_kernel(const int* __restrict__ src, const int* __restrict__ dst,
                            int* __restrict__ cursor, int* __restrict__ csr_src, int E) {
  int e = blockIdx.x * blockDim.x + threadIdx.x;
  if (e < E) {
    int pos = atomicAdd(&cursor[dst[e]], 1);
    csr_src[pos] = src[e];
  }
}

// ---------------- prescale: xs = x * dis[row]  (n x 64, float4) ----------------

__global__ void prescale_kernel(const float* __restrict__ x, const float* __restrict__ dis,
                                float* __restrict__ xs, int n) {
  int i = blockIdx.x * blockDim.x + threadIdx.x;  // over n*16 float4s
  if (i >= n * 16) return;
  int row = i >> 4;
  float4 v = ((const float4*)x)[i];
  float s = dis[row];
  v.x *= s; v.y *= s; v.z *= s; v.w *= s;
  ((float4*)xs)[i] = v;
}

// ---------------- gather (dim 64): agg[d] = dis[d]*(in[d] + sum in[s]) ---------

__global__ void gather64(const int* __restrict__ row_ptr, const int* __restrict__ csr_src,
                         const float* __restrict__ in, const float* __restrict__ dis,
                         float* __restrict__ agg, int n) {
  int node = blockIdx.x * (blockDim.x >> 6) + (threadIdx.x >> 6);
  int lane = threadIdx.x & 63;
  if (node >= n) return;
  int beg = row_ptr[node];
  int end = row_ptr[node + 1];
  float acc = in[(size_t)node * 64 + lane];  // self-loop
  int k = beg;
  for (; k + 3 < end; k += 4) {  // 4 independent loads in flight
    int s0 = csr_src[k];
    int s1 = csr_src[k + 1];
    int s2 = csr_src[k + 2];
    int s3 = csr_src[k + 3];
    float v0 = in[(size_t)s0 * 64 + lane];
    float v1 = in[(size_t)s1 * 64 + lane];
    float v2 = in[(size_t)s2 * 64 + lane];
    float v3 = in[(size_t)s3 * 64 + lane];
    acc += (v0 + v1) + (v2 + v3);
  }
  for (; k < end; ++k) acc += in[(size_t)csr_src[k] * 64 + lane];
  agg[(size_t)node * 64 + lane] = acc * dis[node];
}

// ---------------- tiled GEMM (64-row x 64-col slab) ----------------
// out[r, cb+c] = act( sum_k X[r,k] W[k, cb+c] + b[cb+c] ) [* dis[r]]
// X stride 64, W/out stride ldw. Thread tile 4x4.

__device__ __forceinline__ void fma4(float4& a, float s, const float4 w) {
  a.x = fmaf(s, w.x, a.x);
  a.y = fmaf(s, w.y, a.y);
  a.z = fmaf(s, w.z, a.z);
  a.w = fmaf(s, w.w, a.w);
}

template <bool RELU, bool SCALE>
__global__ __launch_bounds__(256, 4) void gemm64(const float* __restrict__ X,
                                                 const float* __restrict__ W,
                                                 const float* __restrict__ B,
                                                 const float* __restrict__ dis,
                                                 float* __restrict__ y, int n, int ldw) {
  __shared__ float Xs[64 * 68];
  __shared__ float Ws[64 * 64];
  int tid = threadIdx.x;
  int rb = blockIdx.x * 64;
  int cb = blockIdx.y * 64;

  for (int i = tid; i < 1024; i += 256) {
    int k = i >> 4, cq = (i & 15) << 2;
    *(float4*)&Ws[k * 64 + cq] = *(const float4*)&W[(size_t)k * ldw + cb + cq];
  }
  for (int i = tid; i < 1024; i += 256) {
    int r = i >> 4, kq = (i & 15) << 2;
    int gr = rb + r;
    float4 v = make_float4(0.f, 0.f, 0.f, 0.f);
    if (gr < n) v = *(const float4*)&X[(size_t)gr * 64 + kq];
    *(float4*)&Xs[r * 68 + kq] = v;
  }
  __syncthreads();

  int r0 = (tid >> 4) << 2;
  int c0 = (tid & 15) << 2;

  float4 a0 = make_float4(0.f, 0.f, 0.f, 0.f);
  float4 a1 = a0, a2 = a0, a3 = a0;

#pragma unroll 2
  for (int kc = 0; kc < 64; kc += 4) {
    float4 x0 = *(const float4*)&Xs[(r0 + 0) * 68 + kc];
    float4 x1 = *(const float4*)&Xs[(r0 + 1) * 68 + kc];
    float4 x2 = *(const float4*)&Xs[(r0 + 2) * 68 + kc];
    float4 x3 = *(const float4*)&Xs[(r0 + 3) * 68 + kc];
    float4 w0 = *(const float4*)&Ws[(kc + 0) * 64 + c0];
    float4 w1 = *(const float4*)&Ws[(kc + 1) * 64 + c0];
    float4 w2 = *(const float4*)&Ws[(kc + 2) * 64 + c0];
    float4 w3 = *(const float4*)&Ws[(kc + 3) * 64 + c0];
    fma4(a0, x0.x, w0); fma4(a0, x0.y, w1); fma4(a0, x0.z, w2); fma4(a0, x0.w, w3);
    fma4(a1, x1.x, w0); fma4(a1, x1.y, w1); fma4(a1, x1.z, w2); fma4(a1, x1.w, w3);
    fma4(a2, x2.x, w0); fma4(a2, x2.y, w1); fma4(a2, x2.z, w2); fma4(a2, x2.w, w3);
    fma4(a3, x3.x, w0); fma4(a3, x3.y, w1); fma4(a3, x3.z, w2); fma4(a3, x3.w, w3);
  }

  float4 bb = *(const float4*)&B[cb + c0];
  int gr0 = rb + r0;
  size_t base = (size_t)gr0 * ldw + cb + c0;
#pragma unroll
  for (int ri = 0; ri < 4; ++ri) {
    int gr = gr0 + ri;
    if (gr >= n) break;
    float4 v = (ri == 0) ? a0 : (ri == 1) ? a1 : (ri == 2) ? a2 : a3;
    v.x += bb.x; v.y += bb.y; v.z += bb.z; v.w += bb.w;
    if (RELU) {
      v.x = fmaxf(v.x, 0.f); v.y = fmaxf(v.y, 0.f);
      v.z = fmaxf(v.z, 0.f); v.w = fmaxf(v.w, 0.f);
    }
    if (SCALE) {
      float s = dis[gr];
      v.x *= s; v.y *= s; v.z *= s; v.w *= s;
    }
    *(float4*)&y[base + (size_t)ri * ldw] = v;
  }
}

// ---------------- launch ----------------

extern "C" void kernel_launch(void* const* d_in, const int* in_sizes, int n_in,
                              void* d_out, int out_size, void* d_ws, size_t ws_size,
                              hipStream_t stream) {
  const float* x  = (const float*)d_in[0];
  const float* W1 = (const float*)d_in[1];
  const float* b1 = (const float*)d_in[2];
  const float* W2 = (const float*)d_in[3];
  const float* b2 = (const float*)d_in[4];
  const float* W3 = (const float*)d_in[5];
  const float* b3 = (const float*)d_in[6];
  const int*   ei = (const int*)d_in[7];

  const int n = in_sizes[0] / 64;   // 100000
  const int E = in_sizes[7] / 2;    // 1000000
  const int* src = ei;
  const int* dst = ei + E;

  // Workspace: floats dis[n] | bufIn[n*64] | agg[n*64], then ints
  float* dis   = (float*)d_ws;
  float* bufIn = dis + n;
  float* agg   = bufIn + (size_t)n * 64;
  int* deg     = (int*)(agg + (size_t)n * 64);
  int* partial = deg + n;
  int* bsum    = partial + n;
  int* boff    = bsum + 512;
  int* row_ptr = boff + 512;
  int* cursor  = row_ptr + (n + 1);
  int* csr_src = cursor + n;
  float* out = (float*)d_out;

  dim3 blk(256);
  int gN  = (n + 255) / 256;
  int gN1 = (n + 256) / 256;
  int gE  = (E + 255) / 256;
  int gW  = (n + 3) / 4;          // gather: 4 waves (nodes) per block
  int gT  = (n + 63) / 64;        // gemm: 64-row tiles
  int gS  = (n * 16 + 255) / 256; // prescale: float4 granularity

  // --- CSR build + dis ---
  hipMemsetAsync(deg, 0, (size_t)n * sizeof(int), stream);
  hist_kernel<<<gE, blk, 0, stream>>>(dst, deg, E);
  scanA_kernel<<<gN, blk, 0, stream>>>(deg, partial, bsum, n);
  scanB_kernel<<<1, 512, 0, stream>>>(bsum, boff, gN);
  scanC_kernel<<<gN1, blk, 0, stream>>>(partial, boff, deg, row_ptr, cursor, dis, n, E);
  fill_kernel<<<gE, blk, 0, stream>>>(src, dst, cursor, csr_src, E);

  // --- prescale input ---
  prescale_kernel<<<gS, blk, 0, stream>>>(x, dis, bufIn, n);

  // --- Layer 1: gather -> gemm(relu, scale) ---
  gather64<<<gW, blk, 0, stream>>>(row_ptr, csr_src, bufIn, dis, agg, n);
  gemm64<true, true><<<dim3(gT, 1), blk, 0, stream>>>(agg, W1, b1, dis, bufIn, n, 64);

  // --- Layer 2 ---
  gather64<<<gW, blk, 0, stream>>>(row_ptr, csr_src, bufIn, dis, agg, n);
  gemm64<true, true><<<dim3(gT, 1), blk, 0, stream>>>(agg, W2, b2, dis, bufIn, n, 64);

  // --- Layer 3: gather -> gemm(out, 128 cols) ---
  gather64<<<gW, blk, 0, stream>>>(row_ptr, csr_src, bufIn, dis, agg, n);
  gemm64<false, false><<<dim3(gT, 2), blk, 0, stream>>>(agg, W3, b3, dis, out, n, 128);
}

// Round 7
// 418.915 us; speedup vs baseline: 2.3205x; 1.0566x over previous
//
#include <hip/hip_runtime.h>

// GCN 3-layer encoder, aggregate-first form (A_hat commutes with W):
//   per layer: agg = D^-1/2 (A+I) D^-1/2 X   (gather in dim 64)
//              out = act(agg @ W + b) [* dis for next layer's gather input]
// CSR built per call (histogram -> scan -> fill); gather = wave per node,
// 64 lanes = 4 edge slots x 16 float4 feature slices (4 edges per load issue),
// unroll x2 -> 8 rows (2 KB) in flight per wave; cross-edge shfl_xor reduce.
// LESSON (r3/r4): full unroll of the 16-step GEMM K-loop -> 256 VGPR + scratch
// spill. Keep "#pragma unroll 2".
// LESSON (r5): gather is latency/issue-bound (VALUBusy 18%, 3.7 TB/s) -> more
// independent rows in flight per wave, fewer issue slots per edge.

// ---------------- CSR build ----------------

__global__ void hist_kernel(const int* __restrict__ dst, int* __restrict__ deg, int E) {
  int e = blockIdx.x * blockDim.x + threadIdx.x;
  if (e < E) atomicAdd(&deg[dst[e]], 1);
}

__global__ void scanA_kernel(const int* __restrict__ deg, int* __restrict__ partial,
                             int* __restrict__ bsum, int n) {
  __shared__ int tmp[256];
  int t = threadIdx.x;
  int i = blockIdx.x * 256 + t;
  int v = (i < n) ? deg[i] : 0;
  tmp[t] = v;
  __syncthreads();
  for (int off = 1; off < 256; off <<= 1) {
    int a = (t >= off) ? tmp[t - off] : 0;
    __syncthreads();
    tmp[t] += a;
    __syncthreads();
  }
  if (i < n) partial[i] = tmp[t] - v;  // exclusive
  if (t == 255) bsum[blockIdx.x] = tmp[t];
}

__global__ void scanB_kernel(const int* __restrict__ bsum, int* __restrict__ boff, int nb) {
  __shared__ int tmp[512];
  int t = threadIdx.x;
  int v = (t < nb) ? bsum[t] : 0;
  tmp[t] = v;
  __syncthreads();
  for (int off = 1; off < 512; off <<= 1) {
    int a = (t >= off) ? tmp[t - off] : 0;
    __syncthreads();
    tmp[t] += a;
    __syncthreads();
  }
  if (t < nb) boff[t] = tmp[t] - v;  // exclusive
}

__global__ void scanC_kernel(const int* __restrict__ partial, const int* __restrict__ boff,
                             const int* __restrict__ deg, int* __restrict__ row_ptr,
                             int* __restrict__ cursor, float* __restrict__ dis, int n, int E) {
  int i = blockIdx.x * blockDim.x + threadIdx.x;
  if (i < n) {
    int rp = partial[i] + boff[i >> 8];
    row_ptr[i] = rp;
    cursor[i] = rp;
    dis[i] = rsqrtf((float)deg[i] + 1.0f);  // +1 = self-loop
  } else if (i == n) {
    row_ptr[n] = E;
  }
}

__global__ void fill_kernel(const int* __restrict__ src, const int* __restrict__ dst,
                            int* __restrict__ cursor, int* __restrict__ csr_src, int E) {
  int e = blockIdx.x * blockDim.x + threadIdx.x;
  if (e < E) {
    int pos = atomicAdd(&cursor[dst[e]], 1);
    csr_src[pos] = src[e];
  }
}

// ---------------- prescale: xs = x * dis[row]  (n x 64, float4) ----------------

__global__ void prescale_kernel(const float* __restrict__ x, const float* __restrict__ dis,
                                float* __restrict__ xs, int n) {
  int i = blockIdx.x * blockDim.x + threadIdx.x;  // over n*16 float4s
  if (i >= n * 16) return;
  int row = i >> 4;
  float4 v = ((const float4*)x)[i];
  float s = dis[row];
  v.x *= s; v.y *= s; v.z *= s; v.w *= s;
  ((float4*)xs)[i] = v;
}

// ---------------- gather (dim 64): agg[d] = dis[d]*(in[d] + sum in[s]) ---------
// Wave per node. Lane = eg*16 + fs: edge slot eg in [0,4), feature slice fs in
// [0,16) covering floats [4*fs, 4*fs+4). Two edge groups per iteration.

__global__ __launch_bounds__(256) void gather64(const int* __restrict__ row_ptr,
                                                const int* __restrict__ csr_src,
                                                const float* __restrict__ in,
                                                const float* __restrict__ dis,
                                                float* __restrict__ agg, int n) {
  int node = blockIdx.x * (blockDim.x >> 6) + (threadIdx.x >> 6);
  int t = threadIdx.x & 63;
  int eg = t >> 4;   // edge slot 0..3
  int fs = t & 15;   // float4 slice 0..15
  if (node >= n) return;  // wave-uniform (wave = node)
  int beg = row_ptr[node];
  int end = row_ptr[node + 1];

  float4 acc = make_float4(0.f, 0.f, 0.f, 0.f);
  if (eg == 0) acc = *(const float4*)&in[(size_t)node * 64 + fs * 4];  // self-loop

  for (int k = beg; k < end; k += 8) {
    int e0 = k + eg;
    int e1 = k + 4 + eg;
    float4 v0 = make_float4(0.f, 0.f, 0.f, 0.f);
    float4 v1 = make_float4(0.f, 0.f, 0.f, 0.f);
    if (e0 < end) {
      int s = csr_src[e0];
      v0 = *(const float4*)&in[(size_t)s * 64 + fs * 4];
    }
    if (e1 < end) {
      int s = csr_src[e1];
      v1 = *(const float4*)&in[(size_t)s * 64 + fs * 4];
    }
    acc.x += v0.x + v1.x;
    acc.y += v0.y + v1.y;
    acc.z += v0.z + v1.z;
    acc.w += v0.w + v1.w;
  }

  // reduce the 4 edge slots (lanes 16 and 32 apart)
  acc.x += __shfl_xor(acc.x, 16); acc.y += __shfl_xor(acc.y, 16);
  acc.z += __shfl_xor(acc.z, 16); acc.w += __shfl_xor(acc.w, 16);
  acc.x += __shfl_xor(acc.x, 32); acc.y += __shfl_xor(acc.y, 32);
  acc.z += __shfl_xor(acc.z, 32); acc.w += __shfl_xor(acc.w, 32);

  if (eg == 0) {
    float s = dis[node];
    acc.x *= s; acc.y *= s; acc.z *= s; acc.w *= s;
    *(float4*)&agg[(size_t)node * 64 + fs * 4] = acc;
  }
}

// ---------------- tiled GEMM (64-row x 64-col slab) ----------------
// out[r, cb+c] = act( sum_k X[r,k] W[k, cb+c] + b[cb+c] ) [* dis[r]]
// X stride 64, W/out stride ldw. Thread tile 4x4.

__device__ __forceinline__ void fma4(float4& a, float s, const float4 w) {
  a.x = fmaf(s, w.x, a.x);
  a.y = fmaf(s, w.y, a.y);
  a.z = fmaf(s, w.z, a.z);
  a.w = fmaf(s, w.w, a.w);
}

template <bool RELU, bool SCALE>
__global__ __launch_bounds__(256, 4) void gemm64(const float* __restrict__ X,
                                                 const float* __restrict__ W,
                                                 const float* __restrict__ B,
                                                 const float* __restrict__ dis,
                                                 float* __restrict__ y, int n, int ldw) {
  __shared__ float Xs[64 * 68];
  __shared__ float Ws[64 * 64];
  int tid = threadIdx.x;
  int rb = blockIdx.x * 64;
  int cb = blockIdx.y * 64;

  for (int i = tid; i < 1024; i += 256) {
    int k = i >> 4, cq = (i & 15) << 2;
    *(float4*)&Ws[k * 64 + cq] = *(const float4*)&W[(size_t)k * ldw + cb + cq];
  }
  for (int i = tid; i < 1024; i += 256) {
    int r = i >> 4, kq = (i & 15) << 2;
    int gr = rb + r;
    float4 v = make_float4(0.f, 0.f, 0.f, 0.f);
    if (gr < n) v = *(const float4*)&X[(size_t)gr * 64 + kq];
    *(float4*)&Xs[r * 68 + kq] = v;
  }
  __syncthreads();

  int r0 = (tid >> 4) << 2;
  int c0 = (tid & 15) << 2;

  float4 a0 = make_float4(0.f, 0.f, 0.f, 0.f);
  float4 a1 = a0, a2 = a0, a3 = a0;

#pragma unroll 2
  for (int kc = 0; kc < 64; kc += 4) {
    float4 x0 = *(const float4*)&Xs[(r0 + 0) * 68 + kc];
    float4 x1 = *(const float4*)&Xs[(r0 + 1) * 68 + kc];
    float4 x2 = *(const float4*)&Xs[(r0 + 2) * 68 + kc];
    float4 x3 = *(const float4*)&Xs[(r0 + 3) * 68 + kc];
    float4 w0 = *(const float4*)&Ws[(kc + 0) * 64 + c0];
    float4 w1 = *(const float4*)&Ws[(kc + 1) * 64 + c0];
    float4 w2 = *(const float4*)&Ws[(kc + 2) * 64 + c0];
    float4 w3 = *(const float4*)&Ws[(kc + 3) * 64 + c0];
    fma4(a0, x0.x, w0); fma4(a0, x0.y, w1); fma4(a0, x0.z, w2); fma4(a0, x0.w, w3);
    fma4(a1, x1.x, w0); fma4(a1, x1.y, w1); fma4(a1, x1.z, w2); fma4(a1, x1.w, w3);
    fma4(a2, x2.x, w0); fma4(a2, x2.y, w1); fma4(a2, x2.z, w2); fma4(a2, x2.w, w3);
    fma4(a3, x3.x, w0); fma4(a3, x3.y, w1); fma4(a3, x3.z, w2); fma4(a3, x3.w, w3);
  }

  float4 bb = *(const float4*)&B[cb + c0];
  int gr0 = rb + r0;
  size_t base = (size_t)gr0 * ldw + cb + c0;
#pragma unroll
  for (int ri = 0; ri < 4; ++ri) {
    int gr = gr0 + ri;
    if (gr >= n) break;
    float4 v = (ri == 0) ? a0 : (ri == 1) ? a1 : (ri == 2) ? a2 : a3;
    v.x += bb.x; v.y += bb.y; v.z += bb.z; v.w += bb.w;
    if (RELU) {
      v.x = fmaxf(v.x, 0.f); v.y = fmaxf(v.y, 0.f);
      v.z = fmaxf(v.z, 0.f); v.w = fmaxf(v.w, 0.f);
    }
    if (SCALE) {
      float s = dis[gr];
      v.x *= s; v.y *= s; v.z *= s; v.w *= s;
    }
    *(float4*)&y[base + (size_t)ri * ldw] = v;
  }
}

// ---------------- launch ----------------

extern "C" void kernel_launch(void* const* d_in, const int* in_sizes, int n_in,
                              void* d_out, int out_size, void* d_ws, size_t ws_size,
                              hipStream_t stream) {
  const float* x  = (const float*)d_in[0];
  const float* W1 = (const float*)d_in[1];
  const float* b1 = (const float*)d_in[2];
  const float* W2 = (const float*)d_in[3];
  const float* b2 = (const float*)d_in[4];
  const float* W3 = (const float*)d_in[5];
  const float* b3 = (const float*)d_in[6];
  const int*   ei = (const int*)d_in[7];

  const int n = in_sizes[0] / 64;   // 100000
  const int E = in_sizes[7] / 2;    // 1000000
  const int* src = ei;
  const int* dst = ei + E;

  // Workspace: floats dis[n] | bufIn[n*64] | agg[n*64], then ints
  float* dis   = (float*)d_ws;
  float* bufIn = dis + n;
  float* agg   = bufIn + (size_t)n * 64;
  int* deg     = (int*)(agg + (size_t)n * 64);
  int* partial = deg + n;
  int* bsum    = partial + n;
  int* boff    = bsum + 512;
  int* row_ptr = boff + 512;
  int* cursor  = row_ptr + (n + 1);
  int* csr_src = cursor + n;
  float* out = (float*)d_out;

  dim3 blk(256);
  int gN  = (n + 255) / 256;
  int gN1 = (n + 256) / 256;
  int gE  = (E + 255) / 256;
  int gW  = (n + 3) / 4;          // gather: 4 waves (nodes) per block
  int gT  = (n + 63) / 64;        // gemm: 64-row tiles
  int gS  = (n * 16 + 255) / 256; // prescale: float4 granularity

  // --- CSR build + dis ---
  hipMemsetAsync(deg, 0, (size_t)n * sizeof(int), stream);
  hist_kernel<<<gE, blk, 0, stream>>>(dst, deg, E);
  scanA_kernel<<<gN, blk, 0, stream>>>(deg, partial, bsum, n);
  scanB_kernel<<<1, 512, 0, stream>>>(bsum, boff, gN);
  scanC_kernel<<<gN1, blk, 0, stream>>>(partial, boff, deg, row_ptr, cursor, dis, n, E);
  fill_kernel<<<gE, blk, 0, stream>>>(src, dst, cursor, csr_src, E);

  // --- prescale input ---
  prescale_kernel<<<gS, blk, 0, stream>>>(x, dis, bufIn, n);

  // --- Layer 1: gather -> gemm(relu, scale) ---
  gather64<<<gW, blk, 0, stream>>>(row_ptr, csr_src, bufIn, dis, agg, n);
  gemm64<true, true><<<dim3(gT, 1), blk, 0, stream>>>(agg, W1, b1, dis, bufIn, n, 64);

  // --- Layer 2 ---
  gather64<<<gW, blk, 0, stream>>>(row_ptr, csr_src, bufIn, dis, agg, n);
  gemm64<true, true><<<dim3(gT, 1), blk, 0, stream>>>(agg, W2, b2, dis, bufIn, n, 64);

  // --- Layer 3: gather -> gemm(out, 128 cols) ---
  gather64<<<gW, blk, 0, stream>>>(row_ptr, csr_src, bufIn, dis, agg, n);
  gemm64<false, false><<<dim3(gT, 2), blk, 0, stream>>>(agg, W3, b3, dis, out, n, 128);
}

// Round 8
// 396.490 us; speedup vs baseline: 2.4518x; 1.0566x over previous
//
#include <hip/hip_runtime.h>
#include <hip/hip_fp16.h>

// GCN 3-layer encoder, aggregate-first form (A_hat commutes with W):
//   per layer: agg = D^-1/2 (A+I) D^-1/2 X   (gather in dim 64, fp16 staged)
//              out = act(agg @ W + b) [* dis, packed fp16 for next gather]
// CSR built per call (histogram -> scan -> fill); gather = wave per node,
// 64 lanes = 8 edge slots x 8 uint4 slices (8 halves each) -> 8 edges per load
// issue, x2 unroll = 16 rows (2 KB) in flight; cross-edge shfl_xor reduce.
// fp32 accumulation everywhere; fp16 only as the scatter-read storage format.
// LESSON (r3/r4): never take addresses of register data; cap GEMM K-loop
// unroll at 2 (full unroll -> 256 VGPR + scratch spill).
// LESSON (r5/r7): gather is latency/fetch-bound -> fewer bytes per row, more
// independent rows in flight.

// ---------------- CSR build ----------------

__global__ void hist_kernel(const int* __restrict__ dst, int* __restrict__ deg, int E) {
  int e = blockIdx.x * blockDim.x + threadIdx.x;
  if (e < E) atomicAdd(&deg[dst[e]], 1);
}

__global__ void scanA_kernel(const int* __restrict__ deg, int* __restrict__ partial,
                             int* __restrict__ bsum, int n) {
  __shared__ int tmp[256];
  int t = threadIdx.x;
  int i = blockIdx.x * 256 + t;
  int v = (i < n) ? deg[i] : 0;
  tmp[t] = v;
  __syncthreads();
  for (int off = 1; off < 256; off <<= 1) {
    int a = (t >= off) ? tmp[t - off] : 0;
    __syncthreads();
    tmp[t] += a;
    __syncthreads();
  }
  if (i < n) partial[i] = tmp[t] - v;  // exclusive
  if (t == 255) bsum[blockIdx.x] = tmp[t];
}

__global__ void scanB_kernel(const int* __restrict__ bsum, int* __restrict__ boff, int nb) {
  __shared__ int tmp[512];
  int t = threadIdx.x;
  int v = (t < nb) ? bsum[t] : 0;
  tmp[t] = v;
  __syncthreads();
  for (int off = 1; off < 512; off <<= 1) {
    int a = (t >= off) ? tmp[t - off] : 0;
    __syncthreads();
    tmp[t] += a;
    __syncthreads();
  }
  if (t < nb) boff[t] = tmp[t] - v;  // exclusive
}

__global__ void scanC_kernel(const int* __restrict__ partial, const int* __restrict__ boff,
                             const int* __restrict__ deg, int* __restrict__ row_ptr,
                             int* __restrict__ cursor, float* __restrict__ dis, int n, int E) {
  int i = blockIdx.x * blockDim.x + threadIdx.x;
  if (i < n) {
    int rp = partial[i] + boff[i >> 8];
    row_ptr[i] = rp;
    cursor[i] = rp;
    dis[i] = rsqrtf((float)deg[i] + 1.0f);  // +1 = self-loop
  } else if (i == n) {
    row_ptr[n] = E;
  }
}

__global__ void fill_kernel(const int* __restrict__ src, const int* __restrict__ dst,
                            int* __restrict__ cursor, int* __restrict__ csr_src, int E) {
  int e = blockIdx.x * blockDim.x + threadIdx.x;
  if (e < E) {
    int pos = atomicAdd(&cursor[dst[e]], 1);
    csr_src[pos] = src[e];
  }
}

// ---------------- fp16 pack/unpack (register-only bit ops) ----------------

__device__ __forceinline__ unsigned int packh(float a, float b) {
  unsigned int lo = (unsigned int)__half_as_ushort(__float2half_rn(a));
  unsigned int hi = (unsigned int)__half_as_ushort(__float2half_rn(b));
  return lo | (hi << 16);
}

__device__ __forceinline__ void unpack_add(float& x0, float& x1, unsigned int u) {
  x0 += __half2float(__ushort_as_half((unsigned short)(u & 0xffffu)));
  x1 += __half2float(__ushort_as_half((unsigned short)(u >> 16)));
}

// ---------------- prescale: xs = fp16(x * dis[row])  (n x 64) ----------------

__global__ void prescale_h(const float* __restrict__ x, const float* __restrict__ dis,
                           unsigned short* __restrict__ xs, int n) {
  int i = blockIdx.x * blockDim.x + threadIdx.x;  // over n*8 16B-chunks
  if (i >= n * 8) return;
  int row = i >> 3;
  float s = dis[row];
  const float4* p = (const float4*)(x + (size_t)i * 8);
  float4 f0 = p[0];
  float4 f1 = p[1];
  uint4 u;
  u.x = packh(f0.x * s, f0.y * s);
  u.y = packh(f0.z * s, f0.w * s);
  u.z = packh(f1.x * s, f1.y * s);
  u.w = packh(f1.z * s, f1.w * s);
  *(uint4*)(xs + (size_t)i * 8) = u;
}

// ------- gather (dim 64, fp16 in): agg[d] = dis[d]*(in[d] + sum in[s]) -------
// Wave per node. Lane = eg*8 + fs: edge slot eg in [0,8), slice fs in [0,8)
// covering halves [8*fs, 8*fs+8). Two edge groups per iteration (16 edges).

__global__ __launch_bounds__(256) void gather64h(const int* __restrict__ row_ptr,
                                                 const int* __restrict__ csr_src,
                                                 const unsigned short* __restrict__ in,
                                                 const float* __restrict__ dis,
                                                 float* __restrict__ agg, int n) {
  int node = blockIdx.x * (blockDim.x >> 6) + (threadIdx.x >> 6);
  int t = threadIdx.x & 63;
  int eg = t >> 3;  // edge slot 0..7
  int fs = t & 7;   // 16B slice 0..7
  if (node >= n) return;  // wave-uniform

  int beg = row_ptr[node];
  int end = row_ptr[node + 1];

  float a0 = 0.f, a1 = 0.f, a2 = 0.f, a3 = 0.f;
  float a4 = 0.f, a5 = 0.f, a6 = 0.f, a7 = 0.f;

  if (eg == 0) {  // self-loop
    uint4 r = *(const uint4*)(in + (size_t)node * 64 + fs * 8);
    unpack_add(a0, a1, r.x); unpack_add(a2, a3, r.y);
    unpack_add(a4, a5, r.z); unpack_add(a6, a7, r.w);
  }

  for (int k = beg; k < end; k += 16) {
    int e0 = k + eg;
    int e1 = k + 8 + eg;
    if (e0 < end) {
      int s = csr_src[e0];
      uint4 r = *(const uint4*)(in + (size_t)s * 64 + fs * 8);
      unpack_add(a0, a1, r.x); unpack_add(a2, a3, r.y);
      unpack_add(a4, a5, r.z); unpack_add(a6, a7, r.w);
    }
    if (e1 < end) {
      int s = csr_src[e1];
      uint4 r = *(const uint4*)(in + (size_t)s * 64 + fs * 8);
      unpack_add(a0, a1, r.x); unpack_add(a2, a3, r.y);
      unpack_add(a4, a5, r.z); unpack_add(a6, a7, r.w);
    }
  }

  // butterfly over the 8 edge slots (lane strides 8, 16, 32)
#pragma unroll
  for (int m = 8; m <= 32; m <<= 1) {
    a0 += __shfl_xor(a0, m); a1 += __shfl_xor(a1, m);
    a2 += __shfl_xor(a2, m); a3 += __shfl_xor(a3, m);
    a4 += __shfl_xor(a4, m); a5 += __shfl_xor(a5, m);
    a6 += __shfl_xor(a6, m); a7 += __shfl_xor(a7, m);
  }

  if (eg == 0) {
    float sc = dis[node];
    float4 lo = make_float4(a0 * sc, a1 * sc, a2 * sc, a3 * sc);
    float4 hi = make_float4(a4 * sc, a5 * sc, a6 * sc, a7 * sc);
    *(float4*)&agg[(size_t)node * 64 + fs * 8] = lo;
    *(float4*)&agg[(size_t)node * 64 + fs * 8 + 4] = hi;
  }
}

// ---------------- tiled GEMM (64-row x 64-col slab) ----------------
// out[r, cb+c] = act( sum_k X[r,k] W[k, cb+c] + b[cb+c] ) [* dis[r]]
// X stride 64 fp32, W stride ldw. Output: fp32 (yF) or packed fp16 (yH).

__device__ __forceinline__ void fma4(float4& a, float s, const float4 w) {
  a.x = fmaf(s, w.x, a.x);
  a.y = fmaf(s, w.y, a.y);
  a.z = fmaf(s, w.z, a.z);
  a.w = fmaf(s, w.w, a.w);
}

template <bool RELU, bool SCALE, bool OUTH>
__global__ __launch_bounds__(256, 4) void gemm64(const float* __restrict__ X,
                                                 const float* __restrict__ W,
                                                 const float* __restrict__ B,
                                                 const float* __restrict__ dis,
                                                 float* __restrict__ yF,
                                                 unsigned short* __restrict__ yH,
                                                 int n, int ldw) {
  __shared__ float Xs[64 * 68];
  __shared__ float Ws[64 * 64];
  int tid = threadIdx.x;
  int rb = blockIdx.x * 64;
  int cb = blockIdx.y * 64;

  for (int i = tid; i < 1024; i += 256) {
    int k = i >> 4, cq = (i & 15) << 2;
    *(float4*)&Ws[k * 64 + cq] = *(const float4*)&W[(size_t)k * ldw + cb + cq];
  }
  for (int i = tid; i < 1024; i += 256) {
    int r = i >> 4, kq = (i & 15) << 2;
    int gr = rb + r;
    float4 v = make_float4(0.f, 0.f, 0.f, 0.f);
    if (gr < n) v = *(const float4*)&X[(size_t)gr * 64 + kq];
    *(float4*)&Xs[r * 68 + kq] = v;
  }
  __syncthreads();

  int r0 = (tid >> 4) << 2;
  int c0 = (tid & 15) << 2;

  float4 a0 = make_float4(0.f, 0.f, 0.f, 0.f);
  float4 a1 = a0, a2 = a0, a3 = a0;

#pragma unroll 2
  for (int kc = 0; kc < 64; kc += 4) {
    float4 x0 = *(const float4*)&Xs[(r0 + 0) * 68 + kc];
    float4 x1 = *(const float4*)&Xs[(r0 + 1) * 68 + kc];
    float4 x2 = *(const float4*)&Xs[(r0 + 2) * 68 + kc];
    float4 x3 = *(const float4*)&Xs[(r0 + 3) * 68 + kc];
    float4 w0 = *(const float4*)&Ws[(kc + 0) * 64 + c0];
    float4 w1 = *(const float4*)&Ws[(kc + 1) * 64 + c0];
    float4 w2 = *(const float4*)&Ws[(kc + 2) * 64 + c0];
    float4 w3 = *(const float4*)&Ws[(kc + 3) * 64 + c0];
    fma4(a0, x0.x, w0); fma4(a0, x0.y, w1); fma4(a0, x0.z, w2); fma4(a0, x0.w, w3);
    fma4(a1, x1.x, w0); fma4(a1, x1.y, w1); fma4(a1, x1.z, w2); fma4(a1, x1.w, w3);
    fma4(a2, x2.x, w0); fma4(a2, x2.y, w1); fma4(a2, x2.z, w2); fma4(a2, x2.w, w3);
    fma4(a3, x3.x, w0); fma4(a3, x3.y, w1); fma4(a3, x3.z, w2); fma4(a3, x3.w, w3);
  }

  float4 bb = *(const float4*)&B[cb + c0];
  int gr0 = rb + r0;
#pragma unroll
  for (int ri = 0; ri < 4; ++ri) {
    int gr = gr0 + ri;
    if (gr >= n) break;
    float4 v = (ri == 0) ? a0 : (ri == 1) ? a1 : (ri == 2) ? a2 : a3;
    v.x += bb.x; v.y += bb.y; v.z += bb.z; v.w += bb.w;
    if (RELU) {
      v.x = fmaxf(v.x, 0.f); v.y = fmaxf(v.y, 0.f);
      v.z = fmaxf(v.z, 0.f); v.w = fmaxf(v.w, 0.f);
    }
    if (SCALE) {
      float s = dis[gr];
      v.x *= s; v.y *= s; v.z *= s; v.w *= s;
    }
    if (OUTH) {
      uint2 u;
      u.x = packh(v.x, v.y);
      u.y = packh(v.z, v.w);
      *(uint2*)(yH + (size_t)gr * ldw + cb + c0) = u;
    } else {
      *(float4*)&yF[(size_t)gr * ldw + cb + c0] = v;
    }
  }
}

// ---------------- launch ----------------

extern "C" void kernel_launch(void* const* d_in, const int* in_sizes, int n_in,
                              void* d_out, int out_size, void* d_ws, size_t ws_size,
                              hipStream_t stream) {
  const float* x  = (const float*)d_in[0];
  const float* W1 = (const float*)d_in[1];
  const float* b1 = (const float*)d_in[2];
  const float* W2 = (const float*)d_in[3];
  const float* b2 = (const float*)d_in[4];
  const float* W3 = (const float*)d_in[5];
  const float* b3 = (const float*)d_in[6];
  const int*   ei = (const int*)d_in[7];

  const int n = in_sizes[0] / 64;   // 100000
  const int E = in_sizes[7] / 2;    // 1000000
  const int* src = ei;
  const int* dst = ei + E;

  // Workspace: dis[n] f32 | bufIn[n*64] fp16 | agg[n*64] f32 | ints
  float* dis = (float*)d_ws;
  unsigned short* bufIn = (unsigned short*)(dis + n);
  float* agg = (float*)(bufIn + (size_t)n * 64);
  int* deg     = (int*)(agg + (size_t)n * 64);
  int* partial = deg + n;
  int* bsum    = partial + n;
  int* boff    = bsum + 512;
  int* row_ptr = boff + 512;
  int* cursor  = row_ptr + (n + 1);
  int* csr_src = cursor + n;
  float* out = (float*)d_out;

  dim3 blk(256);
  int gN  = (n + 255) / 256;
  int gN1 = (n + 256) / 256;
  int gE  = (E + 255) / 256;
  int gW  = (n + 3) / 4;           // gather: 4 waves (nodes) per block
  int gT  = (n + 63) / 64;         // gemm: 64-row tiles
  int gS  = (n * 8 + 255) / 256;   // prescale: 16B chunks

  // --- CSR build + dis ---
  hipMemsetAsync(deg, 0, (size_t)n * sizeof(int), stream);
  hist_kernel<<<gE, blk, 0, stream>>>(dst, deg, E);
  scanA_kernel<<<gN, blk, 0, stream>>>(deg, partial, bsum, n);
  scanB_kernel<<<1, 512, 0, stream>>>(bsum, boff, gN);
  scanC_kernel<<<gN1, blk, 0, stream>>>(partial, boff, deg, row_ptr, cursor, dis, n, E);
  fill_kernel<<<gE, blk, 0, stream>>>(src, dst, cursor, csr_src, E);

  // --- prescale input to fp16 ---
  prescale_h<<<gS, blk, 0, stream>>>(x, dis, bufIn, n);

  // --- Layer 1: gather -> gemm(relu, scale, fp16 out) ---
  gather64h<<<gW, blk, 0, stream>>>(row_ptr, csr_src, bufIn, dis, agg, n);
  gemm64<true, true, true><<<dim3(gT, 1), blk, 0, stream>>>(agg, W1, b1, dis, nullptr, bufIn, n, 64);

  // --- Layer 2 ---
  gather64h<<<gW, blk, 0, stream>>>(row_ptr, csr_src, bufIn, dis, agg, n);
  gemm64<true, true, true><<<dim3(gT, 1), blk, 0, stream>>>(agg, W2, b2, dis, nullptr, bufIn, n, 64);

  // --- Layer 3: gather -> gemm(fp32 out, 128 cols) ---
  gather64h<<<gW, blk, 0, stream>>>(row_ptr, csr_src, bufIn, dis, agg, n);
  gemm64<false, false, false><<<dim3(gT, 2), blk, 0, stream>>>(agg, W3, b3, dis, out, nullptr, n, 128);
}

// Round 9
// 321.120 us; speedup vs baseline: 3.0272x; 1.2347x over previous
//
#include <hip/hip_runtime.h>
#include <hip/hip_fp16.h>

// GCN 3-layer encoder, aggregate-first form (A_hat commutes with W):
//   per layer: agg = D^-1/2 (A+I) D^-1/2 X   (gather in dim 64, fp16 staged)
//              out = act(agg @ W + b) [* dis, packed fp16 for next gather]
// CSR build: two-level bucketed (bucket = 256 dst nodes) so every random
// scatter lands in a block-owned LDS-cursored window -> no global atomics, no
// cross-XCD partial-line write amplification (r8: fill_kernel wrote 69 MB for
// 4 MB payload).
// Gather: wave per node, 64 lanes = 8 edge slots x 8 uint4 slices; fp32 acc.
// LESSON (r3/r4): never take addresses of register data; cap GEMM K-loop
// unroll at 2 (full unroll -> 256 VGPR + scratch spill).
// LESSON (r5/r7/r8): gather is latency/fetch-bound; fp16 staging halves bytes.

#define NBMAX 512   // max buckets (n <= 131072)
#define EPB   8192  // edges per binning block

// ---------------- bucketed CSR build ----------------

// A: per-block bucket histogram -> hist[block][bucket]
__global__ __launch_bounds__(256) void bin_hist(const int* __restrict__ dst,
                                                int* __restrict__ hist, int E, int NB) {
  __shared__ int cnt[NBMAX];
  for (int i = threadIdx.x; i < NB; i += 256) cnt[i] = 0;
  __syncthreads();
  int base = blockIdx.x * EPB;
  for (int it = 0; it < EPB; it += 256) {
    int e = base + it + threadIdx.x;
    if (e < E) atomicAdd(&cnt[dst[e] >> 8], 1);
  }
  __syncthreads();
  for (int i = threadIdx.x; i < NB; i += 256) hist[(size_t)blockIdx.x * NB + i] = cnt[i];
}

// B1: per bucket, exclusive scan over blocks (in place); totals out.
// Requires nblk <= 256 (E=1e6, EPB=8192 -> 123).
__global__ __launch_bounds__(256) void bucket_prefix(int* __restrict__ hist,
                                                     int* __restrict__ bucket_tot,
                                                     int nblk, int NB) {
  __shared__ int tmp[256];
  int b = blockIdx.x;
  int t = threadIdx.x;
  int v = (t < nblk) ? hist[(size_t)t * NB + b] : 0;
  tmp[t] = v;
  __syncthreads();
  for (int off = 1; off < 256; off <<= 1) {
    int a = (t >= off) ? tmp[t - off] : 0;
    __syncthreads();
    tmp[t] += a;
    __syncthreads();
  }
  if (t < nblk) hist[(size_t)t * NB + b] = tmp[t] - v;  // exclusive over blocks
  if (t == 255) bucket_tot[b] = tmp[255];
}

// B2: exclusive scan of bucket totals -> bucket_off[0..NB], bucket_off[NB]=E.
__global__ __launch_bounds__(512) void bucket_scan(const int* __restrict__ bucket_tot,
                                                   int* __restrict__ bucket_off, int NB, int E) {
  __shared__ int tmp[NBMAX];
  int t = threadIdx.x;
  int v = (t < NB) ? bucket_tot[t] : 0;
  tmp[t] = v;
  __syncthreads();
  for (int off = 1; off < 512; off <<= 1) {
    int a = (t >= off) ? tmp[t - off] : 0;
    __syncthreads();
    tmp[t] += a;
    __syncthreads();
  }
  if (t < NB) bucket_off[t] = tmp[t] - v;
  if (t == 0) bucket_off[NB] = E;
}

// C: scatter (src,dst) pairs into bucket-contiguous regions, LDS cursors.
__global__ __launch_bounds__(256) void bin_scatter(const int* __restrict__ src,
                                                   const int* __restrict__ dst,
                                                   const int* __restrict__ chunk_excl,
                                                   const int* __restrict__ bucket_off,
                                                   int2* __restrict__ pairs, int E, int NB) {
  __shared__ int cur[NBMAX];
  for (int i = threadIdx.x; i < NB; i += 256)
    cur[i] = bucket_off[i] + chunk_excl[(size_t)blockIdx.x * NB + i];
  __syncthreads();
  int base = blockIdx.x * EPB;
  for (int it = 0; it < EPB; it += 256) {
    int e = base + it + threadIdx.x;
    if (e < E) {
      int d = dst[e];
      int pos = atomicAdd(&cur[d >> 8], 1);
      pairs[pos] = make_int2(src[e], d);
    }
  }
}

// D: per bucket: node histogram -> row_ptr + dis; CSR fill with LDS cursors.
__global__ __launch_bounds__(256) void bucket_fill(const int2* __restrict__ pairs,
                                                   const int* __restrict__ bucket_off,
                                                   int* __restrict__ row_ptr,
                                                   int* __restrict__ csr_src,
                                                   float* __restrict__ dis, int n, int NB) {
  __shared__ int cnt[256];
  __shared__ int tmp[256];
  __shared__ int cur[256];
  int b = blockIdx.x;
  int t = threadIdx.x;
  int node_base = b << 8;
  int ebeg = bucket_off[b];
  int eend = bucket_off[b + 1];
  cnt[t] = 0;
  __syncthreads();
  for (int e = ebeg + t; e < eend; e += 256) {
    atomicAdd(&cnt[pairs[e].y - node_base], 1);
  }
  __syncthreads();
  int v = cnt[t];
  tmp[t] = v;
  __syncthreads();
  for (int off = 1; off < 256; off <<= 1) {
    int a = (t >= off) ? tmp[t - off] : 0;
    __syncthreads();
    tmp[t] += a;
    __syncthreads();
  }
  int excl = tmp[t] - v;
  int node = node_base + t;
  if (node < n) {
    row_ptr[node] = ebeg + excl;
    dis[node] = rsqrtf((float)v + 1.0f);  // +1 = self-loop
  }
  cur[t] = ebeg + excl;
  if (b == NB - 1 && t == 0) row_ptr[n] = eend;
  __syncthreads();
  for (int e = ebeg + t; e < eend; e += 256) {
    int2 p = pairs[e];
    int pos = atomicAdd(&cur[p.y - node_base], 1);
    csr_src[pos] = p.x;
  }
}

// ---------------- fp16 pack/unpack (register-only bit ops) ----------------

__device__ __forceinline__ unsigned int packh(float a, float b) {
  unsigned int lo = (unsigned int)__half_as_ushort(__float2half_rn(a));
  unsigned int hi = (unsigned int)__half_as_ushort(__float2half_rn(b));
  return lo | (hi << 16);
}

__device__ __forceinline__ void unpack_add(float& x0, float& x1, unsigned int u) {
  x0 += __half2float(__ushort_as_half((unsigned short)(u & 0xffffu)));
  x1 += __half2float(__ushort_as_half((unsigned short)(u >> 16)));
}

// ---------------- prescale: xs = fp16(x * dis[row])  (n x 64) ----------------

__global__ void prescale_h(const float* __restrict__ x, const float* __restrict__ dis,
                           unsigned short* __restrict__ xs, int n) {
  int i = blockIdx.x * blockDim.x + threadIdx.x;  // over n*8 16B-chunks
  if (i >= n * 8) return;
  int row = i >> 3;
  float s = dis[row];
  const float4* p = (const float4*)(x + (size_t)i * 8);
  float4 f0 = p[0];
  float4 f1 = p[1];
  uint4 u;
  u.x = packh(f0.x * s, f0.y * s);
  u.y = packh(f0.z * s, f0.w * s);
  u.z = packh(f1.x * s, f1.y * s);
  u.w = packh(f1.z * s, f1.w * s);
  *(uint4*)(xs + (size_t)i * 8) = u;
}

// ------- gather (dim 64, fp16 in): agg[d] = dis[d]*(in[d] + sum in[s]) -------
// Wave per node. Lane = eg*8 + fs: edge slot eg in [0,8), slice fs in [0,8)
// covering halves [8*fs, 8*fs+8). Two edge groups per iteration (16 edges).

__global__ __launch_bounds__(256) void gather64h(const int* __restrict__ row_ptr,
                                                 const int* __restrict__ csr_src,
                                                 const unsigned short* __restrict__ in,
                                                 const float* __restrict__ dis,
                                                 float* __restrict__ agg, int n) {
  int node = blockIdx.x * (blockDim.x >> 6) + (threadIdx.x >> 6);
  int t = threadIdx.x & 63;
  int eg = t >> 3;  // edge slot 0..7
  int fs = t & 7;   // 16B slice 0..7
  if (node >= n) return;  // wave-uniform

  int beg = row_ptr[node];
  int end = row_ptr[node + 1];

  float a0 = 0.f, a1 = 0.f, a2 = 0.f, a3 = 0.f;
  float a4 = 0.f, a5 = 0.f, a6 = 0.f, a7 = 0.f;

  if (eg == 0) {  // self-loop
    uint4 r = *(const uint4*)(in + (size_t)node * 64 + fs * 8);
    unpack_add(a0, a1, r.x); unpack_add(a2, a3, r.y);
    unpack_add(a4, a5, r.z); unpack_add(a6, a7, r.w);
  }

  for (int k = beg; k < end; k += 16) {
    int e0 = k + eg;
    int e1 = k + 8 + eg;
    if (e0 < end) {
      int s = csr_src[e0];
      uint4 r = *(const uint4*)(in + (size_t)s * 64 + fs * 8);
      unpack_add(a0, a1, r.x); unpack_add(a2, a3, r.y);
      unpack_add(a4, a5, r.z); unpack_add(a6, a7, r.w);
    }
    if (e1 < end) {
      int s = csr_src[e1];
      uint4 r = *(const uint4*)(in + (size_t)s * 64 + fs * 8);
      unpack_add(a0, a1, r.x); unpack_add(a2, a3, r.y);
      unpack_add(a4, a5, r.z); unpack_add(a6, a7, r.w);
    }
  }

  // butterfly over the 8 edge slots (lane strides 8, 16, 32)
#pragma unroll
  for (int m = 8; m <= 32; m <<= 1) {
    a0 += __shfl_xor(a0, m); a1 += __shfl_xor(a1, m);
    a2 += __shfl_xor(a2, m); a3 += __shfl_xor(a3, m);
    a4 += __shfl_xor(a4, m); a5 += __shfl_xor(a5, m);
    a6 += __shfl_xor(a6, m); a7 += __shfl_xor(a7, m);
  }

  if (eg == 0) {
    float sc = dis[node];
    float4 lo = make_float4(a0 * sc, a1 * sc, a2 * sc, a3 * sc);
    float4 hi = make_float4(a4 * sc, a5 * sc, a6 * sc, a7 * sc);
    *(float4*)&agg[(size_t)node * 64 + fs * 8] = lo;
    *(float4*)&agg[(size_t)node * 64 + fs * 8 + 4] = hi;
  }
}

// ---------------- tiled GEMM (64-row x 64-col slab) ----------------
// out[r, cb+c] = act( sum_k X[r,k] W[k, cb+c] + b[cb+c] ) [* dis[r]]
// X stride 64 fp32, W stride ldw. Output: fp32 (yF) or packed fp16 (yH).

__device__ __forceinline__ void fma4(float4& a, float s, const float4 w) {
  a.x = fmaf(s, w.x, a.x);
  a.y = fmaf(s, w.y, a.y);
  a.z = fmaf(s, w.z, a.z);
  a.w = fmaf(s, w.w, a.w);
}

template <bool RELU, bool SCALE, bool OUTH>
__global__ __launch_bounds__(256, 4) void gemm64(const float* __restrict__ X,
                                                 const float* __restrict__ W,
                                                 const float* __restrict__ B,
                                                 const float* __restrict__ dis,
                                                 float* __restrict__ yF,
                                                 unsigned short* __restrict__ yH,
                                                 int n, int ldw) {
  __shared__ float Xs[64 * 68];
  __shared__ float Ws[64 * 64];
  int tid = threadIdx.x;
  int rb = blockIdx.x * 64;
  int cb = blockIdx.y * 64;

  for (int i = tid; i < 1024; i += 256) {
    int k = i >> 4, cq = (i & 15) << 2;
    *(float4*)&Ws[k * 64 + cq] = *(const float4*)&W[(size_t)k * ldw + cb + cq];
  }
  for (int i = tid; i < 1024; i += 256) {
    int r = i >> 4, kq = (i & 15) << 2;
    int gr = rb + r;
    float4 v = make_float4(0.f, 0.f, 0.f, 0.f);
    if (gr < n) v = *(const float4*)&X[(size_t)gr * 64 + kq];
    *(float4*)&Xs[r * 68 + kq] = v;
  }
  __syncthreads();

  int r0 = (tid >> 4) << 2;
  int c0 = (tid & 15) << 2;

  float4 a0 = make_float4(0.f, 0.f, 0.f, 0.f);
  float4 a1 = a0, a2 = a0, a3 = a0;

#pragma unroll 2
  for (int kc = 0; kc < 64; kc += 4) {
    float4 x0 = *(const float4*)&Xs[(r0 + 0) * 68 + kc];
    float4 x1 = *(const float4*)&Xs[(r0 + 1) * 68 + kc];
    float4 x2 = *(const float4*)&Xs[(r0 + 2) * 68 + kc];
    float4 x3 = *(const float4*)&Xs[(r0 + 3) * 68 + kc];
    float4 w0 = *(const float4*)&Ws[(kc + 0) * 64 + c0];
    float4 w1 = *(const float4*)&Ws[(kc + 1) * 64 + c0];
    float4 w2 = *(const float4*)&Ws[(kc + 2) * 64 + c0];
    float4 w3 = *(const float4*)&Ws[(kc + 3) * 64 + c0];
    fma4(a0, x0.x, w0); fma4(a0, x0.y, w1); fma4(a0, x0.z, w2); fma4(a0, x0.w, w3);
    fma4(a1, x1.x, w0); fma4(a1, x1.y, w1); fma4(a1, x1.z, w2); fma4(a1, x1.w, w3);
    fma4(a2, x2.x, w0); fma4(a2, x2.y, w1); fma4(a2, x2.z, w2); fma4(a2, x2.w, w3);
    fma4(a3, x3.x, w0); fma4(a3, x3.y, w1); fma4(a3, x3.z, w2); fma4(a3, x3.w, w3);
  }

  float4 bb = *(const float4*)&B[cb + c0];
  int gr0 = rb + r0;
#pragma unroll
  for (int ri = 0; ri < 4; ++ri) {
    int gr = gr0 + ri;
    if (gr >= n) break;
    float4 v = (ri == 0) ? a0 : (ri == 1) ? a1 : (ri == 2) ? a2 : a3;
    v.x += bb.x; v.y += bb.y; v.z += bb.z; v.w += bb.w;
    if (RELU) {
      v.x = fmaxf(v.x, 0.f); v.y = fmaxf(v.y, 0.f);
      v.z = fmaxf(v.z, 0.f); v.w = fmaxf(v.w, 0.f);
    }
    if (SCALE) {
      float s = dis[gr];
      v.x *= s; v.y *= s; v.z *= s; v.w *= s;
    }
    if (OUTH) {
      uint2 u;
      u.x = packh(v.x, v.y);
      u.y = packh(v.z, v.w);
      *(uint2*)(yH + (size_t)gr * ldw + cb + c0) = u;
    } else {
      *(float4*)&yF[(size_t)gr * ldw + cb + c0] = v;
    }
  }
}

// ---------------- launch ----------------

extern "C" void kernel_launch(void* const* d_in, const int* in_sizes, int n_in,
                              void* d_out, int out_size, void* d_ws, size_t ws_size,
                              hipStream_t stream) {
  const float* x  = (const float*)d_in[0];
  const float* W1 = (const float*)d_in[1];
  const float* b1 = (const float*)d_in[2];
  const float* W2 = (const float*)d_in[3];
  const float* b2 = (const float*)d_in[4];
  const float* W3 = (const float*)d_in[5];
  const float* b3 = (const float*)d_in[6];
  const int*   ei = (const int*)d_in[7];

  const int n = in_sizes[0] / 64;   // 100000
  const int E = in_sizes[7] / 2;    // 1000000
  const int* src = ei;
  const int* dst = ei + E;

  const int NB    = (n + 255) >> 8;         // buckets (256 nodes each): 391
  const int nblkA = (E + EPB - 1) / EPB;    // binning blocks: 123

  // Workspace: dis[n] f32 | bufIn[n*64] fp16 | agg[n*64] f32 | row_ptr[n+2] |
  //            csr_src[E] | pairs[E] int2 | hist[nblkA*NB] | tot[NB] | off[NB+1]
  float* dis = (float*)d_ws;
  unsigned short* bufIn = (unsigned short*)(dis + n);
  float* agg = (float*)(bufIn + (size_t)n * 64);
  int* row_ptr = (int*)(agg + (size_t)n * 64);
  int* csr_src = row_ptr + (n + 2);         // +2 keeps pairs 8B-aligned
  int2* pairs  = (int2*)(csr_src + E);
  int* hist       = (int*)(pairs + E);
  int* bucket_tot = hist + (size_t)nblkA * NB;
  int* bucket_off = bucket_tot + NB;
  float* out = (float*)d_out;

  dim3 blk(256);
  int gW = (n + 3) / 4;           // gather: 4 waves (nodes) per block
  int gT = (n + 63) / 64;         // gemm: 64-row tiles
  int gS = (n * 8 + 255) / 256;   // prescale: 16B chunks

  // --- bucketed CSR build (+ dis) ---
  bin_hist<<<nblkA, blk, 0, stream>>>(dst, hist, E, NB);
  bucket_prefix<<<NB, blk, 0, stream>>>(hist, bucket_tot, nblkA, NB);
  bucket_scan<<<1, 512, 0, stream>>>(bucket_tot, bucket_off, NB, E);
  bin_scatter<<<nblkA, blk, 0, stream>>>(src, dst, hist, bucket_off, pairs, E, NB);
  bucket_fill<<<NB, blk, 0, stream>>>(pairs, bucket_off, row_ptr, csr_src, dis, n, NB);

  // --- prescale input to fp16 ---
  prescale_h<<<gS, blk, 0, stream>>>(x, dis, bufIn, n);

  // --- Layer 1: gather -> gemm(relu, scale, fp16 out) ---
  gather64h<<<gW, blk, 0, stream>>>(row_ptr, csr_src, bufIn, dis, agg, n);
  gemm64<true, true, true><<<dim3(gT, 1), blk, 0, stream>>>(agg, W1, b1, dis, nullptr, bufIn, n, 64);

  // --- Layer 2 ---
  gather64h<<<gW, blk, 0, stream>>>(row_ptr, csr_src, bufIn, dis, agg, n);
  gemm64<true, true, true><<<dim3(gT, 1), blk, 0, stream>>>(agg, W2, b2, dis, nullptr, bufIn, n, 64);

  // --- Layer 3: gather -> gemm(fp32 out, 128 cols) ---
  gather64h<<<gW, blk, 0, stream>>>(row_ptr, csr_src, bufIn, dis, agg, n);
  gemm64<false, false, false><<<dim3(gT, 2), blk, 0, stream>>>(agg, W3, b3, dis, out, nullptr, n, 128);
}